// Round 5
// baseline (279.891 us; speedup 1.0000x reference)
//
#include <hip/hip_runtime.h>
#include <hip/hip_bf16.h>

#define BATCH 64
#define IN_CH 128
#define ILEN  512
#define OLEN  505
#define OCH   128
#define KDIM  1024    // IN_CH * 8
#define NSTEP 32      // K steps of 32 (NSTEP ≡ 2 mod 3 assumed by the ring loop)
#define NWG   (OLEN * 2)

typedef float f32x4  __attribute__((ext_vector_type(4)));
typedef f32x4 f32x4u __attribute__((aligned(4)));   // x window is only 4B-aligned
typedef short bf16x8 __attribute__((ext_vector_type(8)));

__device__ __forceinline__ short f2bf(float f) {
  union { __hip_bfloat16 h; short s; } u;
  u.h = __float2bfloat16(f);
  return u.s;
}

// Per block (l, oh): GEMM M=64(b) x N=64(o-half) x K=1024, 4 waves x 16 o.
// FULLY BARRIER-FREE, LDS-FREE main loop: every lane loads its own MFMA
// fragments direct global->reg (A: 8 contiguous x floats, L2-resident;
// B: 8 contiguous w floats of its o-row). 3-deep named ring buffers +
// sched_barrier(0) fences pin issue(kc+2)-before-consume(kc), so ~2 chunks
// (20 KB/wave) stay in flight continuously -- no vmcnt(0) drain anywhere.
// (R3 had this dataflow but the compiler sank the loads; the fences + reg
// headroom of __launch_bounds__(256,3) are the fix.)
template <bool USE_TMP>
__global__ __launch_bounds__(256, 3) void lc1d_main(
    const float* __restrict__ x, const float* __restrict__ w,
    const float* __restrict__ bias, float* __restrict__ outp) {
  // bijective XCD swizzle (NWG % 8 != 0)
  const int orig = blockIdx.x;
  const int xcd = orig & 7, idx = orig >> 3;
  const int q = NWG / 8, rm = NWG % 8;
  const int wg = (xcd < rm ? xcd * (q + 1) : rm * (q + 1) + (xcd - rm) * q) + idx;
  const int l  = wg >> 1;
  const int oh = wg & 1;

  const int tid  = threadIdx.x;
  const int lane = tid & 63;
  const int wn   = tid >> 6;        // wave 0..3 -> o 16-slice
  const int r    = lane & 15;
  const int h    = lane >> 4;
  const int o    = oh * 64 + wn * 16 + r;

  const float* __restrict__ wp =
      w + (size_t)l * (OCH * KDIM) + (size_t)o * KDIM + h * 8;
  const float* __restrict__ xp =
      x + (size_t)r * (IN_CH * ILEN) + (size_t)h * ILEN + l;

  f32x4 acc[4];
#pragma unroll
  for (int m = 0; m < 4; ++m) acc[m] = (f32x4){0.f, 0.f, 0.f, 0.f};

  // 3-deep ring of fragment buffers (named, statically indexed)
  f32x4 A0[4][2], A1[4][2], A2[4][2];
  f32x4 B0[2], B1[2], B2[2];

  auto LD = [&](f32x4 (&a)[4][2], f32x4 (&b)[2], int s) {
    const float* xs = xp + (size_t)s * (4 * ILEN);
#pragma unroll
    for (int mt = 0; mt < 4; ++mt) {
      const float* p = xs + (size_t)mt * (16 * IN_CH * ILEN);
      a[mt][0] = *reinterpret_cast<const f32x4u*>(p);
      a[mt][1] = *reinterpret_cast<const f32x4u*>(p + 4);
    }
    const float* q2 = wp + s * 32;
    b[0] = *reinterpret_cast<const f32x4*>(q2);
    b[1] = *reinterpret_cast<const f32x4*>(q2 + 4);
  };

  auto FMA = [&](f32x4 (&a)[4][2], f32x4 (&b)[2]) {
    bf16x8 bfr;
#pragma unroll
    for (int j = 0; j < 4; ++j) {
      bfr[j]     = f2bf(b[0][j]);
      bfr[4 + j] = f2bf(b[1][j]);
    }
#pragma unroll
    for (int mt = 0; mt < 4; ++mt) {
      bf16x8 afr;
#pragma unroll
      for (int j = 0; j < 4; ++j) {
        afr[j]     = f2bf(a[mt][0][j]);
        afr[4 + j] = f2bf(a[mt][1][j]);
      }
      acc[mt] = __builtin_amdgcn_mfma_f32_16x16x32_bf16(afr, bfr, acc[mt], 0, 0, 0);
    }
  };

  LD(A0, B0, 0);
  LD(A1, B1, 1);
  __builtin_amdgcn_sched_barrier(0);
  // NSTEP = 32 = 3*10 + 2: loop covers chunks 0..29, tail does 30,31
  for (int s = 0; s + 4 < NSTEP; s += 3) {
    LD(A2, B2, s + 2);
    __builtin_amdgcn_sched_barrier(0);
    FMA(A0, B0);
    __builtin_amdgcn_sched_barrier(0);
    LD(A0, B0, s + 3);
    __builtin_amdgcn_sched_barrier(0);
    FMA(A1, B1);
    __builtin_amdgcn_sched_barrier(0);
    LD(A1, B1, s + 4);
    __builtin_amdgcn_sched_barrier(0);
    FMA(A2, B2);
    __builtin_amdgcn_sched_barrier(0);
  }
  FMA(A0, B0);   // chunk 30
  FMA(A1, B1);   // chunk 31

  // C/D layout: col(o)=lane&15, row(b)=(lane>>4)*4+j
  if (USE_TMP) {
    float* t = outp + (size_t)l * (BATCH * OCH) + o;  // tmp[l][b][o], coalesced
#pragma unroll
    for (int mt = 0; mt < 4; ++mt)
#pragma unroll
      for (int j = 0; j < 4; ++j) {
        const int b = mt * 16 + h * 4 + j;
        t[(size_t)b * OCH] = acc[mt][j];
      }
  } else {
    const float bv = bias[o * OLEN + l];
#pragma unroll
    for (int mt = 0; mt < 4; ++mt)
#pragma unroll
      for (int j = 0; j < 4; ++j) {
        const int b = mt * 16 + h * 4 + j;
        outp[(size_t)b * (OCH * OLEN) + (size_t)o * OLEN + l] = acc[mt][j] + bv;
      }
  }
}

// tmp[l][b][o] -> out[b][o][l] (+bias), 64x64 LDS tile transpose
__global__ __launch_bounds__(256) void lc1d_tr(const float* __restrict__ tmp,
                                               const float* __restrict__ bias,
                                               float* __restrict__ out) {
  const int l0  = blockIdx.x * 64;
  const int bo0 = blockIdx.y * 64;
  const int tid = threadIdx.x;
  __shared__ float t[64][65];

  const int boj = tid & 63, lq = tid >> 6;
#pragma unroll
  for (int rr = 0; rr < 16; ++rr) {
    const int li = rr * 4 + lq;
    const int l  = l0 + li;
    if (l < OLEN) t[li][boj] = tmp[(size_t)l * (BATCH * OCH) + bo0 + boj];
  }
  __syncthreads();
  const int lj = tid & 63, bq = tid >> 6;
  const int l  = l0 + lj;
#pragma unroll
  for (int rr = 0; rr < 16; ++rr) {
    const int bl = rr * 4 + bq;
    const int bo = bo0 + bl;
    if (l < OLEN) {
      const int oc = bo & (OCH - 1);
      out[(size_t)bo * OLEN + l] = t[lj][bl] + bias[oc * OLEN + l];
    }
  }
}

extern "C" void kernel_launch(void* const* d_in, const int* in_sizes, int n_in,
                              void* d_out, int out_size, void* d_ws, size_t ws_size,
                              hipStream_t stream) {
  const float* x    = (const float*)d_in[0];
  const float* w    = (const float*)d_in[1];
  const float* bias = (const float*)d_in[2];
  float* out        = (float*)d_out;

  const size_t need = (size_t)OLEN * BATCH * OCH * sizeof(float);  // 16.5 MB
  if (ws_size >= need) {
    float* tmp = (float*)d_ws;
    lc1d_main<true><<<dim3(NWG), 256, 0, stream>>>(x, w, bias, tmp);
    lc1d_tr<<<dim3(8, 128), 256, 0, stream>>>(tmp, bias, out);
  } else {
    lc1d_main<false><<<dim3(NWG), 256, 0, stream>>>(x, w, bias, out);
  }
}

// Round 7
// 109.310 us; speedup vs baseline: 2.5605x; 2.5605x over previous
//
#include <hip/hip_runtime.h>
#include <hip/hip_bf16.h>

#define BATCH 64
#define IN_CH 128
#define ILEN  512
#define OLEN  505
#define OCH   128
#define KDIM  1024    // IN_CH * 8
#define BK    64      // K per chunk
#define NCHK  16      // KDIM / BK
#define NWG   (OLEN * 2)

typedef float f32x4  __attribute__((ext_vector_type(4)));
typedef short bf16x8 __attribute__((ext_vector_type(8)));

__device__ __forceinline__ short f2bf(float f) {
  union { __hip_bfloat16 h; short s; } u;
  u.h = __float2bfloat16(f);
  return u.s;
}

// Per block (l, oh): GEMM M=64(b) x N=64(o-half) x K=1024.
// B (weights, 258MB HBM stream): global_load_lds (un-sinkable), DEPTH-3 LDS
//   ring + raw s_barrier + counted vmcnt(20): the barrier waits on loads
//   issued TWO iterations (~1500cy) earlier -> zero exposed HBM latency.
// A (x, L2-resident): reg-staged f32 -> bf16 LDS, 2-deep.
// R6 BUG FIX: A staging registers are now DOUBLE-BUFFERED (aa0/aa1 by chunk
//   parity). R6 had one aa[16]; loadA(kc+2) clobbered it before writeA(kc+1)
//   consumed it -> As held chunk kc+2 where kc+1 belonged (absmax 225).
// vmcnt accounting at iteration kc (issue order):
//   entering: A16(kc+1)+B4(kc+1)=20 outstanding
//   issue A16(kc+2)+B4(kc+2) -> 40
//   writeA(kc+1): compiler waits A16(kc+1) done -> <=24
//   explicit vmcnt(20): B4(kc+1) done; A16(kc+2)+B4(kc+2)=20 stay in flight
template <bool USE_TMP>
__global__ __launch_bounds__(256, 2) void lc1d_main(
    const float* __restrict__ x, const float* __restrict__ w,
    const float* __restrict__ bias, float* __restrict__ outp) {
  // bijective XCD swizzle (NWG % 8 != 0): contiguous l-chunk per XCD
  const int orig = blockIdx.x;
  const int xcd = orig & 7, idx = orig >> 3;
  const int q = NWG / 8, rm = NWG % 8;
  const int wg = (xcd < rm ? xcd * (q + 1) : rm * (q + 1) + (xcd - rm) * q) + idx;
  const int l  = wg >> 1;
  const int oh = wg & 1;

  const int tid  = threadIdx.x;
  const int lane = tid & 63;
  const int wn   = tid >> 6;        // wave 0..3 -> o 16-slice
  const int r    = lane & 15;
  const int h    = lane >> 4;

  __shared__ float Bs[3][BK * 64];  // 48 KB, row ob(256B), chunk c'=c^swz(ob)
  __shared__ short As[2][BK * 64];  // 16 KB, As[b][kk ^ ((b&7)<<3)]

  f32x4 acc[4];
#pragma unroll
  for (int m = 0; m < 4; ++m) acc[m] = (f32x4){0.f, 0.f, 0.f, 0.f};

  const float* __restrict__ wl =
      w + (size_t)l * (OCH * KDIM) + (size_t)oh * 64 * KDIM;

  // ---- B staging map: dest = base + lane*16 (HW: wave-uniform + lane*size) ----
  const int so  = tid >> 4;                           // 0..15: ob = it*16+so
  const int sc  = tid & 15;                           // dest 16B-chunk
  const int ssw = ((so & 7) << 1) | ((so >> 3) & 1);  // swz(ob)

  // ---- A staging map ----
  const int kk  = tid & 63;
  const int tb  = tid >> 6;
  const int il  = kk >> 3;
  const int kof = kk & 7;

  float aa0[16], aa1[16];   // chunk-parity double buffer (R6 fix)

  auto loadA = [&](float (&aa)[16], int kc) {
    const float* xb = x + (size_t)(kc * 8 + il) * ILEN + l + kof;
#pragma unroll
    for (int it = 0; it < 16; ++it)
      aa[it] = xb[(size_t)(it * 4 + tb) * (IN_CH * ILEN)];
  };
  auto writeA = [&](const float (&aa)[16], int buf) {
#pragma unroll
    for (int it = 0; it < 16; ++it) {
      const int b = it * 4 + tb;
      As[buf][b * 64 + (kk ^ ((b & 7) << 3))] = f2bf(aa[it]);
    }
  };
  auto stageB = [&](int buf, int kc) {
#pragma unroll
    for (int it = 0; it < 4; ++it) {
      const int ob = it * 16 + so;
      const float* src = wl + (size_t)ob * KDIM + kc * BK + (sc ^ ssw) * 4;
      __builtin_amdgcn_global_load_lds(
          (const __attribute__((address_space(1))) void*)src,
          (__attribute__((address_space(3))) void*)&Bs[buf][ob * 64 + sc * 4],
          16, 0, 0);
    }
  };

  const int rsw = ((r & 7) << 1) | ((r >> 3) & 1);
  auto compute = [&](int bB, int bA) {
    const int ob = wn * 16 + r;
#pragma unroll
    for (int ks = 0; ks < 2; ++ks) {
      const int c0 = ks * 8 + h * 2;
      const f32x4 blo = *reinterpret_cast<const f32x4*>(
          &Bs[bB][ob * 64 + ((c0) ^ rsw) * 4]);
      const f32x4 bhi = *reinterpret_cast<const f32x4*>(
          &Bs[bB][ob * 64 + ((c0 + 1) ^ rsw) * 4]);
      bf16x8 bfr;
#pragma unroll
      for (int j = 0; j < 4; ++j) {
        bfr[j]     = f2bf(blo[j]);
        bfr[4 + j] = f2bf(bhi[j]);
      }
#pragma unroll
      for (int mt = 0; mt < 4; ++mt) {
        const int b = mt * 16 + r;
        const bf16x8 afr = *reinterpret_cast<const bf16x8*>(
            &As[bA][b * 64 + ((ks * 32 + h * 8) ^ ((b & 7) << 3))]);
        acc[mt] = __builtin_amdgcn_mfma_f32_16x16x32_bf16(afr, bfr, acc[mt], 0, 0, 0);
      }
    }
  };

  // ---- prologue: {Bs[0],As[0] ready; B(1) in flight; chunk1 in aa1} ----
  loadA(aa0, 0);
  stageB(0, 0);
  writeA(aa0, 0);                    // waits A16(0) -> vmcnt(4); B(0) flying
  loadA(aa1, 1);
  stageB(1, 1);
  asm volatile("s_waitcnt vmcnt(20) lgkmcnt(0)" ::: "memory");  // B(0) done
  __builtin_amdgcn_sched_barrier(0);
  __builtin_amdgcn_s_barrier();
  __builtin_amdgcn_sched_barrier(0);

#pragma unroll
  for (int kc = 0; kc < NCHK; ++kc) {
    if (kc + 2 < NCHK) {             // issue 2-ahead: fly across next barrier
      if ((kc & 1) == 0) loadA(aa0, kc + 2); else loadA(aa1, kc + 2);
      stageB((kc + 2) % 3, kc + 2);
    }
    __builtin_amdgcn_sched_barrier(0);
    compute(kc % 3, kc & 1);
    if (kc + 1 < NCHK) {
      if ((kc & 1) == 0) writeA(aa1, 1); else writeA(aa0, 0);  // chunk kc+1
      if (kc + 2 < NCHK) {
        asm volatile("s_waitcnt vmcnt(20) lgkmcnt(0)" ::: "memory");
      } else {
        asm volatile("s_waitcnt vmcnt(0) lgkmcnt(0)" ::: "memory");
      }
      __builtin_amdgcn_sched_barrier(0);
      __builtin_amdgcn_s_barrier();
      __builtin_amdgcn_sched_barrier(0);
    }
  }

  // ---- epilogue: C/D layout col(o)=lane&15, row(b)=(lane>>4)*4+j ----
  const int og = oh * 64 + wn * 16 + r;
  if (USE_TMP) {
    float* t = outp + (size_t)l * (BATCH * OCH) + og;  // tmp[l][b][o], coalesced
#pragma unroll
    for (int mt = 0; mt < 4; ++mt)
#pragma unroll
      for (int j = 0; j < 4; ++j) {
        const int b = mt * 16 + h * 4 + j;
        t[(size_t)b * OCH] = acc[mt][j];
      }
  } else {
    const float bv = bias[og * OLEN + l];
#pragma unroll
    for (int mt = 0; mt < 4; ++mt)
#pragma unroll
      for (int j = 0; j < 4; ++j) {
        const int b = mt * 16 + h * 4 + j;
        outp[(size_t)b * (OCH * OLEN) + (size_t)og * OLEN + l] = acc[mt][j] + bv;
      }
  }
}

// tmp[l][b][o] -> out[b][o][l] (+bias), 64x64 LDS tile transpose
__global__ __launch_bounds__(256) void lc1d_tr(const float* __restrict__ tmp,
                                               const float* __restrict__ bias,
                                               float* __restrict__ out) {
  const int l0  = blockIdx.x * 64;
  const int bo0 = blockIdx.y * 64;
  const int tid = threadIdx.x;
  __shared__ float t[64][65];

  const int boj = tid & 63, lq = tid >> 6;
#pragma unroll
  for (int rr = 0; rr < 16; ++rr) {
    const int li = rr * 4 + lq;
    const int l  = l0 + li;
    if (l < OLEN) t[li][boj] = tmp[(size_t)l * (BATCH * OCH) + bo0 + boj];
  }
  __syncthreads();
  const int lj = tid & 63, bq = tid >> 6;
  const int l  = l0 + lj;
#pragma unroll
  for (int rr = 0; rr < 16; ++rr) {
    const int bl = rr * 4 + bq;
    const int bo = bo0 + bl;
    if (l < OLEN) {
      const int oc = bo & (OCH - 1);
      out[(size_t)bo * OLEN + l] = t[lj][bl] + bias[oc * OLEN + l];
    }
  }
}

extern "C" void kernel_launch(void* const* d_in, const int* in_sizes, int n_in,
                              void* d_out, int out_size, void* d_ws, size_t ws_size,
                              hipStream_t stream) {
  const float* x    = (const float*)d_in[0];
  const float* w    = (const float*)d_in[1];
  const float* bias = (const float*)d_in[2];
  float* out        = (float*)d_out;

  const size_t need = (size_t)OLEN * BATCH * OCH * sizeof(float);  // 16.5 MB
  if (ws_size >= need) {
    float* tmp = (float*)d_ws;
    lc1d_main<true><<<dim3(NWG), 256, 0, stream>>>(x, w, bias, tmp);
    lc1d_tr<<<dim3(8, 128), 256, 0, stream>>>(tmp, bias, out);
  } else {
    lc1d_main<false><<<dim3(NWG), 256, 0, stream>>>(x, w, bias, out);
  }
}

// Round 8
// 101.700 us; speedup vs baseline: 2.7521x; 1.0748x over previous
//
#include <hip/hip_runtime.h>
#include <hip/hip_bf16.h>

#define BATCH 64
#define IN_CH 128
#define ILEN  512
#define OLEN  505
#define OCH   128
#define KDIM  1024    // IN_CH * 8
#define BK    64      // K per chunk
#define NCHK  16      // KDIM / BK
#define NWG   OLEN    // ONE block per l: all 505 resident at once (no tail)

typedef float f32x4  __attribute__((ext_vector_type(4)));
typedef short bf16x8 __attribute__((ext_vector_type(8)));

__device__ __forceinline__ short f2bf(float f) {
  union { __hip_bfloat16 h; short s; } u;
  u.h = __float2bfloat16(f);
  return u.s;
}

// Per block (l): GEMM M=64(b) x N=128(o, both halves) x K=1024.
// vs R7: grid 1010->505 (single uniform resident round, tail eliminated),
// A loaded ONCE per l (was 2x), w consumed as one 512KB slab per block.
// Counted-vmcnt schedule (R7-verified):
//   entering iter kc: A16(kc+1) outstanding (16)
//   issue B8(kc+1) -> 24; issue A16(kc+2) -> 40
//   writeA(kc+1): implicit wait A16(kc+1) retired -> vmcnt<=24
//   explicit vmcnt(16): retires B8(kc+1); A16(kc+2) flies across barrier
template <bool USE_TMP>
__global__ __launch_bounds__(256, 2) void lc1d_main(
    const float* __restrict__ x, const float* __restrict__ w,
    const float* __restrict__ bias, float* __restrict__ outp) {
  // bijective XCD swizzle (NWG=505, 505%8=1): contiguous l-chunk per XCD
  const int orig = blockIdx.x;
  const int xcd = orig & 7, idx = orig >> 3;
  const int q = NWG / 8, rm = NWG % 8;
  const int l = (xcd < rm ? xcd * (q + 1) : rm * (q + 1) + (xcd - rm) * q) + idx;

  const int tid  = threadIdx.x;
  const int lane = tid & 63;
  const int wn   = tid >> 6;        // wave 0..3 -> o 16-slice within each half
  const int r    = lane & 15;
  const int h    = lane >> 4;

  __shared__ float Bs[2][2][BK * 64];  // 64 KB: [buf][oh], row ob(256B), chunk c'=c^swz
  __shared__ short As[2][BK * 64];     // 16 KB: As[b][kk ^ ((b&7)<<3)]

  f32x4 acc[2][4];
#pragma unroll
  for (int oh = 0; oh < 2; ++oh)
#pragma unroll
    for (int m = 0; m < 4; ++m) acc[oh][m] = (f32x4){0.f, 0.f, 0.f, 0.f};

  const float* __restrict__ wl = w + (size_t)l * (OCH * KDIM);

  // ---- B staging map (R7-verified): dest byte = base(it,wave) + lane*16 ----
  const int so  = tid >> 4;                           // 0..15: ob = it*16+so
  const int sc  = tid & 15;                           // dest 16B-chunk
  const int ssw = ((so & 7) << 1) | ((so >> 3) & 1);  // swz(ob)

  // ---- A staging map ----
  const int kk  = tid & 63;
  const int tb  = tid >> 6;
  const int il  = kk >> 3;
  const int kof = kk & 7;

  float aa0[16], aa1[16];   // chunk-parity double buffer

  auto loadA = [&](float (&aa)[16], int kc) {
    const float* xb = x + (size_t)(kc * 8 + il) * ILEN + l + kof;
#pragma unroll
    for (int it = 0; it < 16; ++it)
      aa[it] = xb[(size_t)(it * 4 + tb) * (IN_CH * ILEN)];
  };
  auto writeA = [&](const float (&aa)[16], int buf) {
#pragma unroll
    for (int it = 0; it < 16; ++it) {
      const int b = it * 4 + tb;
      As[buf][b * 64 + (kk ^ ((b & 7) << 3))] = f2bf(aa[it]);
    }
  };
  auto stageB = [&](int buf, int kc, int oh) {
    const float* wo = wl + (size_t)oh * 64 * KDIM;
#pragma unroll
    for (int it = 0; it < 4; ++it) {
      const int ob = it * 16 + so;
      const float* src = wo + (size_t)ob * KDIM + kc * BK + (sc ^ ssw) * 4;
      __builtin_amdgcn_global_load_lds(
          (const __attribute__((address_space(1))) void*)src,
          (__attribute__((address_space(3))) void*)&Bs[buf][oh][ob * 64 + sc * 4],
          16, 0, 0);
    }
  };

  const int rsw = ((r & 7) << 1) | ((r >> 3) & 1);
  auto compute = [&](int cur, int oh) {
    const int ob = wn * 16 + r;
#pragma unroll
    for (int ks = 0; ks < 2; ++ks) {
      const int c0 = ks * 8 + h * 2;
      const f32x4 blo = *reinterpret_cast<const f32x4*>(
          &Bs[cur][oh][ob * 64 + ((c0) ^ rsw) * 4]);
      const f32x4 bhi = *reinterpret_cast<const f32x4*>(
          &Bs[cur][oh][ob * 64 + ((c0 + 1) ^ rsw) * 4]);
      bf16x8 bfr;
#pragma unroll
      for (int j = 0; j < 4; ++j) {
        bfr[j]     = f2bf(blo[j]);
        bfr[4 + j] = f2bf(bhi[j]);
      }
#pragma unroll
      for (int mt = 0; mt < 4; ++mt) {
        const int b = mt * 16 + r;
        const bf16x8 afr = *reinterpret_cast<const bf16x8*>(
            &As[cur][b * 64 + ((ks * 32 + h * 8) ^ ((b & 7) << 3))]);
        acc[oh][mt] =
            __builtin_amdgcn_mfma_f32_16x16x32_bf16(afr, bfr, acc[oh][mt], 0, 0, 0);
      }
    }
  };

  // ---- prologue: {Bs[0],As[0] ready; chunk1 A in aa1} ----
  loadA(aa0, 0);
  stageB(0, 0, 0);
  stageB(0, 0, 1);
  writeA(aa0, 0);                    // implicit wait A16(0) -> vmcnt<=8
  loadA(aa1, 1);
  asm volatile("s_waitcnt vmcnt(16) lgkmcnt(0)" ::: "memory");  // B8(0) done
  __builtin_amdgcn_sched_barrier(0);
  __builtin_amdgcn_s_barrier();
  __builtin_amdgcn_sched_barrier(0);

  // one sub-step; aaW = buffer holding chunk kc+1 (to write), aaL = load target (kc+2)
  auto step = [&](int kc, float (&aaW)[16], float (&aaL)[16]) {
    if (kc + 1 < NCHK) {
      const int nxt = (kc + 1) & 1;
      stageB(nxt, kc + 1, 0);
      stageB(nxt, kc + 1, 1);
    }
    if (kc + 2 < NCHK) loadA(aaL, kc + 2);
    __builtin_amdgcn_sched_barrier(0);
    const int cur = kc & 1;
    compute(cur, 0);
    compute(cur, 1);
    if (kc + 1 < NCHK) {
      writeA(aaW, (kc + 1) & 1);     // implicit wait A16(kc+1) -> vmcnt<=24
      if (kc + 2 < NCHK) {
        asm volatile("s_waitcnt vmcnt(16) lgkmcnt(0)" ::: "memory");
      } else {
        asm volatile("s_waitcnt vmcnt(0) lgkmcnt(0)" ::: "memory");
      }
      __builtin_amdgcn_sched_barrier(0);
      __builtin_amdgcn_s_barrier();
      __builtin_amdgcn_sched_barrier(0);
    }
  };

  for (int kc = 0; kc < NCHK; kc += 2) {
    step(kc, aa1, aa0);       // even kc: write chunk kc+1 from aa1, load kc+2 -> aa0
    step(kc + 1, aa0, aa1);   // odd  kc: write chunk kc+2 from aa0, load kc+3 -> aa1
  }

  // ---- epilogue: C/D layout col(o)=lane&15, row(b)=(lane>>4)*4+j ----
#pragma unroll
  for (int oh = 0; oh < 2; ++oh) {
    const int og = oh * 64 + wn * 16 + r;
    if (USE_TMP) {
      float* t = outp + (size_t)l * (BATCH * OCH) + og;  // tmp[l][b][o], coalesced
#pragma unroll
      for (int mt = 0; mt < 4; ++mt)
#pragma unroll
        for (int j = 0; j < 4; ++j) {
          const int b = mt * 16 + h * 4 + j;
          t[(size_t)b * OCH] = acc[oh][mt][j];
        }
    } else {
      const float bv = bias[og * OLEN + l];
#pragma unroll
      for (int mt = 0; mt < 4; ++mt)
#pragma unroll
        for (int j = 0; j < 4; ++j) {
          const int b = mt * 16 + h * 4 + j;
          outp[(size_t)b * (OCH * OLEN) + (size_t)og * OLEN + l] = acc[oh][mt][j] + bv;
        }
    }
  }
}

// tmp[l][b][o] -> out[b][o][l] (+bias), 64x64 LDS tile transpose
__global__ __launch_bounds__(256) void lc1d_tr(const float* __restrict__ tmp,
                                               const float* __restrict__ bias,
                                               float* __restrict__ out) {
  const int l0  = blockIdx.x * 64;
  const int bo0 = blockIdx.y * 64;
  const int tid = threadIdx.x;
  __shared__ float t[64][65];

  const int boj = tid & 63, lq = tid >> 6;
#pragma unroll
  for (int rr = 0; rr < 16; ++rr) {
    const int li = rr * 4 + lq;
    const int l  = l0 + li;
    if (l < OLEN) t[li][boj] = tmp[(size_t)l * (BATCH * OCH) + bo0 + boj];
  }
  __syncthreads();
  const int lj = tid & 63, bq = tid >> 6;
  const int l  = l0 + lj;
#pragma unroll
  for (int rr = 0; rr < 16; ++rr) {
    const int bl = rr * 4 + bq;
    const int bo = bo0 + bl;
    if (l < OLEN) {
      const int oc = bo & (OCH - 1);
      out[(size_t)bo * OLEN + l] = t[lj][bl] + bias[oc * OLEN + l];
    }
  }
}

extern "C" void kernel_launch(void* const* d_in, const int* in_sizes, int n_in,
                              void* d_out, int out_size, void* d_ws, size_t ws_size,
                              hipStream_t stream) {
  const float* x    = (const float*)d_in[0];
  const float* w    = (const float*)d_in[1];
  const float* bias = (const float*)d_in[2];
  float* out        = (float*)d_out;

  const size_t need = (size_t)OLEN * BATCH * OCH * sizeof(float);  // 16.5 MB
  if (ws_size >= need) {
    float* tmp = (float*)d_ws;
    lc1d_main<true><<<dim3(NWG), 256, 0, stream>>>(x, w, bias, tmp);
    lc1d_tr<<<dim3(8, 128), 256, 0, stream>>>(tmp, bias, out);
  } else {
    lc1d_main<false><<<dim3(NWG), 256, 0, stream>>>(x, w, bias, out);
  }
}